// Round 8
// baseline (191.344 us; speedup 1.0000x reference)
//
#include <hip/hip_runtime.h>
#include <stdint.h>

typedef unsigned short u16;
typedef unsigned int   u32;
typedef __attribute__((ext_vector_type(8))) short  bf16x8;
typedef __attribute__((ext_vector_type(4))) float  f32x4;
typedef __attribute__((ext_vector_type(4))) u32    u32x4;
typedef __attribute__((ext_vector_type(2))) u32    u32x2;

#define L_SEQ 2048
#define DMODEL 256
// B*H = 32, rows = 65536

// round-to-nearest-even f32 -> bf16
__device__ __forceinline__ u16 f2bf(float x){
  u32 u = __float_as_uint(x);
  return (u16)((u + 0x7FFFu + ((u >> 16) & 1u)) >> 16);
}

__device__ __forceinline__ u32 pack2(float a, float b){
  return (u32)f2bf(a) | ((u32)f2bf(b) << 16);
}

__device__ __forceinline__ void gload_lds16(const void* g, void* l){
  __builtin_amdgcn_global_load_lds(
      (const __attribute__((address_space(1))) u32*)g,
      (__attribute__((address_space(3))) u32*)l, 16, 0, 0);
}

// ---------------- xPos tables: packed (c,s) float2, [pos][hi=128] ----------
__global__ void k_tables(float2* __restrict__ tq2, float2* __restrict__ tk2){
  int idx = blockIdx.x * 256 + threadIdx.x;     // 2048*128 = 262144
  int n = idx >> 7, hi = idx & 127;
  float fn = (float)n, fi = (float)hi;
  float invf = exp2f(-(fi * (1.0f/128.0f)) * 13.2877124f);   // 10000^(-hi/128)
  float ang = fn * invf;
  float s = sinf(ang), c = cosf(ang);
  float sv = (2.0f * fi + 102.4f) * (1.0f / 358.4f);
  float sc = exp2f((fn * (1.0f/512.0f)) * log2f(sv));
  float2 q; q.x = c * sc;  q.y = s * sc;
  tq2[idx] = q;
  float inv = 1.0f / sc;
  float2 k; k.x = c * inv; k.y = s * inv;
  tk2[idx] = k;
}

// ---------------- W bf16, fragment-major: wt[w][kb][c][k32] ----------------
// wt[((w*8 + (k>>5))*256 + c)*32 + (k&31)] = W_w[k][c]
// -> a wf fragment-load instruction reads 1KB fully contiguous per wave.
__global__ void k_wt(const float* __restrict__ wq, const float* __restrict__ wk,
                     const float* __restrict__ wv, u16* __restrict__ wt){
  int idx = blockIdx.x * 256 + threadIdx.x;     // 3*65536
  int w = idx >> 16, r = idx & 65535;
  int c = r >> 8, k = r & 255;
  const float* src = (w == 0) ? wq : ((w == 1) ? wk : wv);
  size_t dst = ((size_t)(w * 8 + (k >> 5)) * 256 + c) * 32 + (k & 31);
  wt[dst] = f2bf(src[k * 256 + c]);
}

// ---------------- X -> bf16, stored as pre-swizzled LDS tile image ----------
// Xb[row][sw] (16B chunks), sw = chunk ^ (row&7). Enables global_load_lds
// staging in k_proj with conflict-free swizzled ds_reads.
__global__ void k_xbf(const float* __restrict__ X, u16* __restrict__ Xb){
  int idx = blockIdx.x * 256 + threadIdx.x;     // 65536*32 chunk ids
  int row = idx >> 5, chunk = idx & 31;
  const float4* src = (const float4*)(X + (size_t)row * 256 + chunk * 8);
  float4 a = src[0], b = src[1];
  u32x4 v;
  v.x = pack2(a.x, a.y); v.y = pack2(a.z, a.w);
  v.z = pack2(b.x, b.y); v.w = pack2(b.z, b.w);
  *(u32x4*)((char*)Xb + (size_t)row * 512 + ((chunk ^ (row & 7)) * 16)) = v;
}

// ---------------- fused QKV projection + xPos (+ V transpose) -------------
// grid (1024 row-tiles, 6 = wsel*2 + colhalf), block 256 (4 waves).
// Block: 64 rows x 128 cols of ONE weight. Wave: 64 rows x 32 cols.
// W fragments (16 x bf16x8 = 64 VGPR) are loop-invariant registers loaded
// ONCE per block; the kb loop is pure ds_read_b128 + MFMA. Q/K computed
// TRANSPOSED (mfma(W,X)): lane owns 4 consecutive d at fixed pos.
__global__ __launch_bounds__(256, 4) void k_proj(
    const u16* __restrict__ Xb, const u16* __restrict__ Wt,
    const float2* __restrict__ tq2, const float2* __restrict__ tk2,
    u16* __restrict__ Qx, u16* __restrict__ Kx, u16* __restrict__ VT)
{
  __shared__ u16 ldsX[64 * 256];                // 32 KiB (swizzled image)
  const int rt = blockIdx.x;
  const int wsel = blockIdx.y >> 1, ch = blockIdx.y & 1;
  const int tid = threadIdx.x;
  const int lane = tid & 63, w = tid >> 6;
  const int h = lane >> 4, l15 = lane & 15;
  const int row0 = rt * 64;
  const int bh = rt >> 5;                       // 32 row-tiles per (b,h)
  const int col0 = ch * 128 + w * 32;

  // ---- resident W fragments: wreg[a][kb], a = 16-col group (2 per wave)
  bf16x8 wreg[2][8];
  {
    const u16* wb = Wt + (size_t)(wsel * 8) * 8192 + (col0 + l15) * 32 + h * 8;
#pragma unroll
    for (int a = 0; a < 2; ++a)
#pragma unroll
      for (int kb = 0; kb < 8; ++kb)
        wreg[a][kb] = *(const bf16x8*)(wb + kb * 8192 + a * 512);
  }

  // ---- stage X tile: direct global->LDS, linear copy of swizzled image
  {
    const u16* xbase = Xb + (size_t)row0 * 256;
#pragma unroll
    for (int t = 0; t < 8; ++t){
      int idx = (w * 8 + t) * 64 + lane;        // 16B chunk id in tile
      gload_lds16(xbase + idx * 8, (char*)ldsX + (w * 8 + t) * 1024);
    }
  }
  __syncthreads();

  f32x4 acc[8] = {};                            // 32 AGPR
#pragma unroll
  for (int kb = 0; kb < 8; ++kb){
    bf16x8 xf[4];
#pragma unroll
    for (int b = 0; b < 4; ++b){
      int r = b * 16 + l15;
      int sw = (kb * 4 + h) ^ (r & 7);
      xf[b] = *(const bf16x8*)((const char*)ldsX + r * 512 + sw * 16);
    }
    if (wsel < 2){
#pragma unroll
      for (int a = 0; a < 2; ++a)
#pragma unroll
        for (int b = 0; b < 4; ++b)
          acc[a * 4 + b] = __builtin_amdgcn_mfma_f32_16x16x32_bf16(
              wreg[a][kb], xf[b], acc[a * 4 + b], 0, 0, 0);
    } else {
#pragma unroll
      for (int b = 0; b < 4; ++b)
#pragma unroll
        for (int a = 0; a < 2; ++a)
          acc[b * 2 + a] = __builtin_amdgcn_mfma_f32_16x16x32_bf16(
              xf[b], wreg[a][kb], acc[b * 2 + a], 0, 0, 0);
    }
  }

  if (wsel == 2){
    // V: acc[b=posfrag][a=dfrag]; lane holds 4 consecutive pos at fixed d
#pragma unroll
    for (int b = 0; b < 4; ++b){
      int pos0 = (row0 + b * 16 + h * 4) & 2047;
#pragma unroll
      for (int a = 0; a < 2; ++a){
        int d = col0 + a * 16 + l15;
        f32x4 v = acc[b * 2 + a];
        u32x2 p2; p2.x = pack2(v.x, v.y); p2.y = pack2(v.z, v.w);
        *(u32x2*)(VT + ((size_t)bh * DMODEL + d) * 2048 + pos0) = p2;
      }
    }
  } else {
    // Q/K: acc[a=dfrag][b=posfrag]; lane holds 4 consecutive d at fixed pos
    const float2* tt = (wsel == 0) ? tq2 : tk2;
    u16* Od = (wsel == 0) ? Qx : Kx;
#pragma unroll
    for (int a = 0; a < 2; ++a){
      int d0 = col0 + a * 16 + h * 4;           // 4-aligned
#pragma unroll
      for (int b = 0; b < 4; ++b){
        int n = row0 + b * 16 + l15;
        int pos = n & 2047;
        f32x4 v = acc[a * 4 + b];
        float4 t = *(const float4*)(tt + pos * 128 + (d0 >> 1));
        float y0 = v.x * t.x - v.y * t.y;       // even d: x*c - x(d+1)*s
        float y1 = v.y * t.x + v.x * t.y;       // odd d:  x*c + x(d-1)*s
        float y2 = v.z * t.z - v.w * t.w;
        float y3 = v.w * t.z + v.z * t.w;
        u32x2 p2; p2.x = pack2(y0, y1); p2.y = pack2(y2, y3);
        *(u32x2*)(Od + (size_t)n * 256 + d0) = p2;
      }
    }
  }
}

// ---------------- banded decayed attention ----------------
// grid 512 = 32 bh * 16 n-chunks(128). block 512 (8 waves x 16 rows).
__global__ __launch_bounds__(512) void k_attn(
    const u16* __restrict__ Qx, const u16* __restrict__ Kx,
    const u16* __restrict__ VT, float* __restrict__ out)
{
  __shared__ char smem[65536];
  u16* ldsK = (u16*)smem;                 // [64 m][256 d] bf16, swizzled
  u16* ldsV = (u16*)(smem + 32768);       // [256 d][64 m] bf16, swizzled

  const int bid = blockIdx.x;
  const int bh = bid >> 4, i = bid & 15;
  const int tid = threadIdx.x;
  const int lane = tid & 63, w = tid >> 6;
  const int h = lane >> 4, l15 = lane & 15;
  const int n_g = i * 128 + w * 16 + l15;

  // Q B-fragments (k-contiguous from row n_g)
  bf16x8 q[8];
  const u16* qbase = Qx + ((size_t)bh * 2048 + n_g) * 256;
#pragma unroll
  for (int kb = 0; kb < 8; ++kb)
    q[kb] = *(const bf16x8*)(qbase + kb * 32 + h * 8);

  f32x4 ot[16] = {};   // O^T: 16 d-tiles x (16d x 16n)

  int j_lo = 2 * i - 4; if (j_lo < 0) j_lo = 0;
  const int j_hi = 2 * i + 1;
  const float L2G = -0.04580369f;          // log2(0.96875)

  for (int j = j_lo; j <= j_hi; ++j){
    // ---- stage K tile and V^T tile (pre-swizzled source, linear LDS dest)
    {
      const u16* kbase = Kx + ((size_t)bh * 2048 + j * 64) * 256;
#pragma unroll
      for (int t = 0; t < 4; ++t){
        int s = (w * 4 + t) * 64 + lane;
        int m = s >> 5, c = s & 31;
        gload_lds16(kbase + m * 256 + ((c ^ (m & 7)) * 8),
                    (char*)ldsK + (w * 4 + t) * 1024);
      }
      const u16* vbase = VT + (size_t)bh * DMODEL * 2048 + j * 64;
#pragma unroll
      for (int t = 0; t < 4; ++t){
        int s = (w * 4 + t) * 64 + lane;
        int d = s >> 3, c = s & 7;
        gload_lds16(vbase + (size_t)d * 2048 + ((c ^ (d & 7)) * 8),
                    (char*)ldsV + (w * 4 + t) * 1024);
      }
    }
    __syncthreads();

    if (i * 128 + w * 16 + 15 >= j * 64){     // wave has any unmasked pairs
      // ---- S^T = K · Q^T  (4 m-tiles x K=256)
      f32x4 sacc[4] = {};
#pragma unroll
      for (int kb = 0; kb < 8; ++kb){
#pragma unroll
        for (int mt = 0; mt < 4; ++mt){
          int m = mt * 16 + l15;
          int chunk = kb * 4 + h;
          bf16x8 a = *(const bf16x8*)((const char*)ldsK + m * 512 +
                                      ((chunk ^ (m & 7)) * 16));
          sacc[mt] = __builtin_amdgcn_mfma_f32_16x16x32_bf16(
              a, q[kb], sacc[mt], 0, 0, 0);
        }
      }
      // ---- decay weight + pack to bf16 pairs (per group of 4 m)
      u32 dA[4], dB[4];
#pragma unroll
      for (int mt = 0; mt < 4; ++mt){
        int m0 = j * 64 + mt * 16 + h * 4;
        int dl = n_g - m0;
        float v0 = (dl     >= 0) ? sacc[mt].x * exp2f((float)(dl    ) * L2G) : 0.0f;
        float v1 = (dl - 1 >= 0) ? sacc[mt].y * exp2f((float)(dl - 1) * L2G) : 0.0f;
        float v2 = (dl - 2 >= 0) ? sacc[mt].z * exp2f((float)(dl - 2) * L2G) : 0.0f;
        float v3 = (dl - 3 >= 0) ? sacc[mt].w * exp2f((float)(dl - 3) * L2G) : 0.0f;
        dA[mt] = pack2(v0, v1);
        dB[mt] = pack2(v2, v3);
      }
      // ---- build PV B-frags in-register (shuffle S^T C-layout -> B-layout)
      int s0 = l15 + 32 * (h & 1);
      int s1 = s0 + 16;
      bool lo = (h < 2);
#pragma unroll
      for (int kt = 0; kt < 2; ++kt){
        u32 a0 = (u32)__shfl((int)dA[2 * kt],     s0, 64);
        u32 a1 = (u32)__shfl((int)dA[2 * kt + 1], s0, 64);
        u32 b0 = (u32)__shfl((int)dB[2 * kt],     s0, 64);
        u32 b1 = (u32)__shfl((int)dB[2 * kt + 1], s0, 64);
        u32 a2 = (u32)__shfl((int)dA[2 * kt],     s1, 64);
        u32 a3 = (u32)__shfl((int)dA[2 * kt + 1], s1, 64);
        u32 b2 = (u32)__shfl((int)dB[2 * kt],     s1, 64);
        u32 b3 = (u32)__shfl((int)dB[2 * kt + 1], s1, 64);
        union { u32 u[4]; bf16x8 v; } uu;
        uu.u[0] = lo ? a0 : a1;
        uu.u[1] = lo ? b0 : b1;
        uu.u[2] = lo ? a2 : a3;
        uu.u[3] = lo ? b2 : b3;
        bf16x8 bfrag = uu.v;
        // ---- O^T += V^T · P^T
#pragma unroll
        for (int dt = 0; dt < 16; ++dt){
          int d = dt * 16 + l15;
          int chunk = kt * 4 + h;
          bf16x8 a = *(const bf16x8*)((const char*)ldsV + d * 128 +
                                      ((chunk ^ (d & 7)) * 16));
          ot[dt] = __builtin_amdgcn_mfma_f32_16x16x32_bf16(
              a, bfrag, ot[dt], 0, 0, 0);
        }
      }
    }
    __syncthreads();
  }

  // ---- write O (f32): lane holds 4 consecutive d at fixed n -> float4
  float* obase = out + ((size_t)bh * 2048 + n_g) * 256;
#pragma unroll
  for (int dt = 0; dt < 16; ++dt)
    *(f32x4*)(obase + dt * 16 + h * 4) = ot[dt];
}

// ---------------- launch ----------------
extern "C" void kernel_launch(void* const* d_in, const int* in_sizes, int n_in,
                              void* d_out, int out_size, void* d_ws, size_t ws_size,
                              hipStream_t stream)
{
  (void)in_sizes; (void)n_in; (void)out_size; (void)ws_size;
  const float* X  = (const float*)d_in[0];
  const float* WQ = (const float*)d_in[1];
  const float* WK = (const float*)d_in[2];
  const float* WV = (const float*)d_in[3];
  float* out = (float*)d_out;

  char* ws = (char*)d_ws;
  float2* tq2 = (float2*)ws;                     // 2 MiB  [2048][128] (c,s)
  float2* tk2 = (float2*)(ws + (2u << 20));      // 2 MiB
  u16* wt = (u16*)(ws + (4u << 20));             // 384 KiB
  u16* qx = (u16*)(ws + 4718592);                // 32 MiB
  u16* kx = (u16*)(ws + 38273024);               // 32 MiB
  u16* vt = (u16*)(ws + 71827456);               // 32 MiB  (end ~100.5 MiB)

  // Xb (32 MiB) lives in d_out (64 MiB): written by k_xbf, consumed by
  // k_proj, then fully overwritten by k_attn's output. Deterministic.
  u16* xb = (u16*)d_out;

  k_tables<<<dim3(1024), dim3(256), 0, stream>>>(tq2, tk2);
  k_wt<<<dim3(768), dim3(256), 0, stream>>>(WQ, WK, WV, wt);
  k_xbf<<<dim3(8192), dim3(256), 0, stream>>>(X, xb);
  k_proj<<<dim3(1024, 6), dim3(256), 0, stream>>>(xb, wt, tq2, tk2, qx, kx, vt);
  k_attn<<<dim3(512), dim3(512), 0, stream>>>(qx, kx, vt, out);
}

// Round 9
// 161.745 us; speedup vs baseline: 1.1830x; 1.1830x over previous
//
#include <hip/hip_runtime.h>
#include <stdint.h>

typedef unsigned short u16;
typedef unsigned int   u32;
typedef __attribute__((ext_vector_type(8))) short  bf16x8;
typedef __attribute__((ext_vector_type(4))) float  f32x4;
typedef __attribute__((ext_vector_type(4))) u32    u32x4;
typedef __attribute__((ext_vector_type(2))) u32    u32x2;

#define L_SEQ 2048
#define DMODEL 256
// B*H = 32, rows = 65536

// round-to-nearest-even f32 -> bf16
__device__ __forceinline__ u16 f2bf(float x){
  u32 u = __float_as_uint(x);
  return (u16)((u + 0x7FFFu + ((u >> 16) & 1u)) >> 16);
}

__device__ __forceinline__ u32 pack2(float a, float b){
  return (u32)f2bf(a) | ((u32)f2bf(b) << 16);
}

__device__ __forceinline__ void gload_lds16(const void* g, void* l){
  __builtin_amdgcn_global_load_lds(
      (const __attribute__((address_space(1))) u32*)g,
      (__attribute__((address_space(3))) u32*)l, 16, 0, 0);
}

// ---------------- xPos tables: packed (c,s) float2, [pos][hi=128] ----------
__global__ void k_tables(float2* __restrict__ tq2, float2* __restrict__ tk2){
  int idx = blockIdx.x * 256 + threadIdx.x;     // 2048*128 = 262144
  int n = idx >> 7, hi = idx & 127;
  float fn = (float)n, fi = (float)hi;
  float invf = exp2f(-(fi * (1.0f/128.0f)) * 13.2877124f);   // 10000^(-hi/128)
  float ang = fn * invf;
  float s = sinf(ang), c = cosf(ang);
  float sv = (2.0f * fi + 102.4f) * (1.0f / 358.4f);
  float sc = exp2f((fn * (1.0f/512.0f)) * log2f(sv));
  float2 q; q.x = c * sc;  q.y = s * sc;
  tq2[idx] = q;
  float inv = 1.0f / sc;
  float2 k; k.x = c * inv; k.y = s * inv;
  tk2[idx] = k;
}

// -------- W -> bf16 chunk-planar pre-swizzled image Wt2[kc][col768][p][8] ----
// Wt2[((kc*768+col)*8+p)*8+e] = W_wsel[kc*64 + (p^(col&7))*8 + e][c]
// (wsel = col>>8, c = col&255). Staged linearly to LDS[col][p]; swizzled
// ds_read at p = chunk ^ (col&7) is then conflict-free.
__global__ void k_wt(const float* __restrict__ wq, const float* __restrict__ wk,
                     const float* __restrict__ wv, u16* __restrict__ wt2){
  int idx = blockIdx.x * 256 + threadIdx.x;     // 4*768*8 = 24576 chunks
  int kc = idx / 6144, r = idx % 6144;
  int col = r >> 3, p = r & 7;
  int j = p ^ (col & 7);
  int wsel = col >> 8, c = col & 255;
  const float* src = (wsel == 0) ? wq : ((wsel == 1) ? wk : wv);
  int k0 = kc * 64 + j * 8;
  u32x4 v;
  v.x = pack2(src[(k0+0)*256 + c], src[(k0+1)*256 + c]);
  v.y = pack2(src[(k0+2)*256 + c], src[(k0+3)*256 + c]);
  v.z = pack2(src[(k0+4)*256 + c], src[(k0+5)*256 + c]);
  v.w = pack2(src[(k0+6)*256 + c], src[(k0+7)*256 + c]);
  *(u32x4*)(wt2 + (size_t)idx * 8) = v;
}

// -------- X -> bf16 chunk-planar pre-swizzled image Xb2[kc][row][p][8] ------
// Xb2[((kc*65536+row)*8+p)*8..] = X[row][kc*64 + (p^(row&7))*8 ..+8]
__global__ void k_xbf(const float* __restrict__ X, u16* __restrict__ Xb2){
  int idx = blockIdx.x * 256 + threadIdx.x;     // 65536*32 chunk ids
  int row = idx >> 5, g = idx & 31;
  int kc = g >> 3, j = g & 7;
  int p = j ^ (row & 7);
  const float4* src = (const float4*)(X + (size_t)row * 256 + g * 8);
  float4 a = src[0], b = src[1];
  u32x4 v;
  v.x = pack2(a.x, a.y); v.y = pack2(a.z, a.w);
  v.z = pack2(b.x, b.y); v.w = pack2(b.z, b.w);
  *(u32x4*)(Xb2 + (((size_t)kc * 65536 + row) * 8 + p) * 8) = v;
}

// ---------------- fused QKV projection + xPos (+ V transpose) -------------
// One GEMM: A = X (65536x256), B = [WQ|WK|WV] (256x768).
// grid (6 coltiles, 512 rowtiles) - coltiles in x so the 6 blocks sharing an
// X rowtile dispatch adjacently (L2/L3-shared). Block 256 (4 waves, 2x2),
// tile 128x128, wave 64x64 (acc 64 AGPR = m97 shape). K staged in 4 chunks
// of 64 via global_load_lds from pre-swizzled images; swizzled ds_read_b128.
// Q/K coltiles: acc = mfma(wf,xf) -> lane holds 4 consecutive d at fixed pos
// (in-lane xPos rotation). V coltiles: acc = mfma(xf,wf) -> VT store.
__global__ __launch_bounds__(256, 2) void k_proj(
    const u16* __restrict__ Xb2, const u16* __restrict__ Wt2,
    const float2* __restrict__ tq2, const float2* __restrict__ tk2,
    u16* __restrict__ Qx, u16* __restrict__ Kx, u16* __restrict__ VT)
{
  __shared__ u16 ldsX[128 * 64];                // 16 KiB
  __shared__ u16 ldsW[128 * 64];                // 16 KiB
  const int ct = blockIdx.x;                    // 0..5
  const int wsel = ct >> 1;
  const int mcol0 = (ct & 1) * 128;             // col offset within matrix
  const int rt = blockIdx.y;
  const int row0 = rt * 128;
  const int bh = rt >> 4;                       // 16 rowtiles per (b,h)
  const int tid = threadIdx.x;
  const int lane = tid & 63, wid = tid >> 6;
  const int h = lane >> 4, l15 = lane & 15;
  const int wrg = wid >> 1, wcg = wid & 1;      // wave row/col group

  f32x4 acc[4][4] = {};                         // 64 AGPR

  for (int kc = 0; kc < 4; ++kc){
    const u16* xsrc = Xb2 + ((size_t)kc * 65536 + row0) * 64;
    const u16* wsrc = Wt2 + ((size_t)kc * 768 + ct * 128) * 64;
#pragma unroll
    for (int t = 0; t < 4; ++t){
      int ci = t * 256 + tid;                   // 16B chunk id (1024 each)
      gload_lds16(xsrc + ci * 8, (char*)ldsX + (t * 256 + wid * 64) * 16);
      gload_lds16(wsrc + ci * 8, (char*)ldsW + (t * 256 + wid * 64) * 16);
    }
    __syncthreads();

#pragma unroll
    for (int kb = 0; kb < 2; ++kb){
      bf16x8 xf[4], wf[4];
#pragma unroll
      for (int b = 0; b < 4; ++b){
        int r = wrg * 64 + b * 16 + l15;
        int p = (kb * 4 + h) ^ (r & 7);
        xf[b] = *(const bf16x8*)((const char*)ldsX + r * 128 + p * 16);
      }
#pragma unroll
      for (int a = 0; a < 4; ++a){
        int c = wcg * 64 + a * 16 + l15;
        int p = (kb * 4 + h) ^ (c & 7);
        wf[a] = *(const bf16x8*)((const char*)ldsW + c * 128 + p * 16);
      }
      if (wsel < 2){
#pragma unroll
        for (int a = 0; a < 4; ++a)
#pragma unroll
          for (int b = 0; b < 4; ++b)
            acc[a][b] = __builtin_amdgcn_mfma_f32_16x16x32_bf16(
                wf[a], xf[b], acc[a][b], 0, 0, 0);
      } else {
#pragma unroll
        for (int b = 0; b < 4; ++b)
#pragma unroll
          for (int a = 0; a < 4; ++a)
            acc[b][a] = __builtin_amdgcn_mfma_f32_16x16x32_bf16(
                xf[b], wf[a], acc[b][a], 0, 0, 0);
      }
    }
    __syncthreads();
  }

  if (wsel == 2){
    // V: acc[b=posfrag][a=dfrag]; lane holds 4 consecutive pos at fixed d
#pragma unroll
    for (int b = 0; b < 4; ++b){
      int pos0 = (row0 + wrg * 64 + b * 16 + h * 4) & 2047;
#pragma unroll
      for (int a = 0; a < 4; ++a){
        int d = mcol0 + wcg * 64 + a * 16 + l15;
        f32x4 v = acc[b][a];
        u32x2 p2; p2.x = pack2(v.x, v.y); p2.y = pack2(v.z, v.w);
        *(u32x2*)(VT + ((size_t)bh * DMODEL + d) * 2048 + pos0) = p2;
      }
    }
  } else {
    // Q/K: acc[a=dfrag][b=posfrag]; lane holds 4 consecutive d at fixed pos
    const float2* tt = (wsel == 0) ? tq2 : tk2;
    u16* Od = (wsel == 0) ? Qx : Kx;
#pragma unroll
    for (int a = 0; a < 4; ++a){
      int d0 = mcol0 + wcg * 64 + a * 16 + h * 4;   // 4-aligned
#pragma unroll
      for (int b = 0; b < 4; ++b){
        int n = row0 + wrg * 64 + b * 16 + l15;
        int pos = n & 2047;
        f32x4 v = acc[a][b];
        float4 t = *(const float4*)(tt + pos * 128 + (d0 >> 1));
        float y0 = v.x * t.x - v.y * t.y;           // even d: x*c - x(d+1)*s
        float y1 = v.y * t.x + v.x * t.y;           // odd d:  x*c + x(d-1)*s
        float y2 = v.z * t.z - v.w * t.w;
        float y3 = v.w * t.z + v.z * t.w;
        u32x2 p2; p2.x = pack2(y0, y1); p2.y = pack2(y2, y3);
        *(u32x2*)(Od + (size_t)n * 256 + d0) = p2;
      }
    }
  }
}

// ---------------- banded decayed attention ----------------
// grid 512 = 32 bh * 16 n-chunks(128). block 512 (8 waves x 16 rows).
__global__ __launch_bounds__(512) void k_attn(
    const u16* __restrict__ Qx, const u16* __restrict__ Kx,
    const u16* __restrict__ VT, float* __restrict__ out)
{
  __shared__ char smem[65536];
  u16* ldsK = (u16*)smem;                 // [64 m][256 d] bf16, swizzled
  u16* ldsV = (u16*)(smem + 32768);       // [256 d][64 m] bf16, swizzled

  const int bid = blockIdx.x;
  const int bh = bid >> 4, i = bid & 15;
  const int tid = threadIdx.x;
  const int lane = tid & 63, w = tid >> 6;
  const int h = lane >> 4, l15 = lane & 15;
  const int n_g = i * 128 + w * 16 + l15;

  // Q B-fragments (k-contiguous from row n_g)
  bf16x8 q[8];
  const u16* qbase = Qx + ((size_t)bh * 2048 + n_g) * 256;
#pragma unroll
  for (int kb = 0; kb < 8; ++kb)
    q[kb] = *(const bf16x8*)(qbase + kb * 32 + h * 8);

  f32x4 ot[16] = {};   // O^T: 16 d-tiles x (16d x 16n)

  int j_lo = 2 * i - 4; if (j_lo < 0) j_lo = 0;
  const int j_hi = 2 * i + 1;
  const float L2G = -0.04580369f;          // log2(0.96875)

  for (int j = j_lo; j <= j_hi; ++j){
    // ---- stage K tile and V^T tile (pre-swizzled source, linear LDS dest)
    {
      const u16* kbase = Kx + ((size_t)bh * 2048 + j * 64) * 256;
#pragma unroll
      for (int t = 0; t < 4; ++t){
        int s = (w * 4 + t) * 64 + lane;
        int m = s >> 5, c = s & 31;
        gload_lds16(kbase + m * 256 + ((c ^ (m & 7)) * 8),
                    (char*)ldsK + (w * 4 + t) * 1024);
      }
      const u16* vbase = VT + (size_t)bh * DMODEL * 2048 + j * 64;
#pragma unroll
      for (int t = 0; t < 4; ++t){
        int s = (w * 4 + t) * 64 + lane;
        int d = s >> 3, c = s & 7;
        gload_lds16(vbase + (size_t)d * 2048 + ((c ^ (d & 7)) * 8),
                    (char*)ldsV + (w * 4 + t) * 1024);
      }
    }
    __syncthreads();

    if (i * 128 + w * 16 + 15 >= j * 64){     // wave has any unmasked pairs
      // ---- S^T = K · Q^T  (4 m-tiles x K=256)
      f32x4 sacc[4] = {};
#pragma unroll
      for (int kb = 0; kb < 8; ++kb){
#pragma unroll
        for (int mt = 0; mt < 4; ++mt){
          int m = mt * 16 + l15;
          int chunk = kb * 4 + h;
          bf16x8 a = *(const bf16x8*)((const char*)ldsK + m * 512 +
                                      ((chunk ^ (m & 7)) * 16));
          sacc[mt] = __builtin_amdgcn_mfma_f32_16x16x32_bf16(
              a, q[kb], sacc[mt], 0, 0, 0);
        }
      }
      // ---- decay weight + pack to bf16 pairs (per group of 4 m)
      u32 dA[4], dB[4];
#pragma unroll
      for (int mt = 0; mt < 4; ++mt){
        int m0 = j * 64 + mt * 16 + h * 4;
        int dl = n_g - m0;
        float v0 = (dl     >= 0) ? sacc[mt].x * exp2f((float)(dl    ) * L2G) : 0.0f;
        float v1 = (dl - 1 >= 0) ? sacc[mt].y * exp2f((float)(dl - 1) * L2G) : 0.0f;
        float v2 = (dl - 2 >= 0) ? sacc[mt].z * exp2f((float)(dl - 2) * L2G) : 0.0f;
        float v3 = (dl - 3 >= 0) ? sacc[mt].w * exp2f((float)(dl - 3) * L2G) : 0.0f;
        dA[mt] = pack2(v0, v1);
        dB[mt] = pack2(v2, v3);
      }
      // ---- build PV B-frags in-register (shuffle S^T C-layout -> B-layout)
      int s0 = l15 + 32 * (h & 1);
      int s1 = s0 + 16;
      bool lo = (h < 2);
#pragma unroll
      for (int kt = 0; kt < 2; ++kt){
        u32 a0 = (u32)__shfl((int)dA[2 * kt],     s0, 64);
        u32 a1 = (u32)__shfl((int)dA[2 * kt + 1], s0, 64);
        u32 b0 = (u32)__shfl((int)dB[2 * kt],     s0, 64);
        u32 b1 = (u32)__shfl((int)dB[2 * kt + 1], s0, 64);
        u32 a2 = (u32)__shfl((int)dA[2 * kt],     s1, 64);
        u32 a3 = (u32)__shfl((int)dA[2 * kt + 1], s1, 64);
        u32 b2 = (u32)__shfl((int)dB[2 * kt],     s1, 64);
        u32 b3 = (u32)__shfl((int)dB[2 * kt + 1], s1, 64);
        union { u32 u[4]; bf16x8 v; } uu;
        uu.u[0] = lo ? a0 : a1;
        uu.u[1] = lo ? b0 : b1;
        uu.u[2] = lo ? a2 : a3;
        uu.u[3] = lo ? b2 : b3;
        bf16x8 bfrag = uu.v;
        // ---- O^T += V^T · P^T
#pragma unroll
        for (int dt = 0; dt < 16; ++dt){
          int d = dt * 16 + l15;
          int chunk = kt * 4 + h;
          bf16x8 a = *(const bf16x8*)((const char*)ldsV + d * 128 +
                                      ((chunk ^ (d & 7)) * 16));
          ot[dt] = __builtin_amdgcn_mfma_f32_16x16x32_bf16(
              a, bfrag, ot[dt], 0, 0, 0);
        }
      }
    }
    __syncthreads();
  }

  // ---- write O (f32): lane holds 4 consecutive d at fixed n -> float4
  float* obase = out + ((size_t)bh * 2048 + n_g) * 256;
#pragma unroll
  for (int dt = 0; dt < 16; ++dt)
    *(f32x4*)(obase + dt * 16 + h * 4) = ot[dt];
}

// ---------------- launch ----------------
extern "C" void kernel_launch(void* const* d_in, const int* in_sizes, int n_in,
                              void* d_out, int out_size, void* d_ws, size_t ws_size,
                              hipStream_t stream)
{
  (void)in_sizes; (void)n_in; (void)out_size; (void)ws_size;
  const float* X  = (const float*)d_in[0];
  const float* WQ = (const float*)d_in[1];
  const float* WK = (const float*)d_in[2];
  const float* WV = (const float*)d_in[3];
  float* out = (float*)d_out;

  char* ws = (char*)d_ws;
  float2* tq2 = (float2*)ws;                     // 2 MiB  [2048][128] (c,s)
  float2* tk2 = (float2*)(ws + (2u << 20));      // 2 MiB
  u16* wt2 = (u16*)(ws + (4u << 20));            // 384 KiB chunk-planar
  u16* qx = (u16*)(ws + 4718592);                // 32 MiB
  u16* kx = (u16*)(ws + 38273024);               // 32 MiB
  u16* vt = (u16*)(ws + 71827456);               // 32 MiB  (end ~100.5 MiB)

  // Xb2 (32 MiB) lives in d_out (64 MiB): written by k_xbf, consumed by
  // k_proj, then fully overwritten by k_attn's output. Deterministic.
  u16* xb2 = (u16*)d_out;

  k_tables<<<dim3(1024), dim3(256), 0, stream>>>(tq2, tk2);
  k_wt<<<dim3(96), dim3(256), 0, stream>>>(WQ, WK, WV, wt2);
  k_xbf<<<dim3(8192), dim3(256), 0, stream>>>(X, xb2);
  k_proj<<<dim3(6, 512), dim3(256), 0, stream>>>(xb2, wt2, tq2, tk2, qx, kx, vt);
  k_attn<<<dim3(512), dim3(512), 0, stream>>>(qx, kx, vt, out);
}

// Round 10
// 139.681 us; speedup vs baseline: 1.3699x; 1.1580x over previous
//
#include <hip/hip_runtime.h>
#include <stdint.h>

typedef unsigned short u16;
typedef unsigned int   u32;
typedef __attribute__((ext_vector_type(8))) short  bf16x8;
typedef __attribute__((ext_vector_type(4))) float  f32x4;
typedef __attribute__((ext_vector_type(4))) u32    u32x4;
typedef __attribute__((ext_vector_type(2))) u32    u32x2;

#define L_SEQ 2048
#define DMODEL 256
// B*H = 32, rows = 65536

// round-to-nearest-even f32 -> bf16
__device__ __forceinline__ u16 f2bf(float x){
  u32 u = __float_as_uint(x);
  return (u16)((u + 0x7FFFu + ((u >> 16) & 1u)) >> 16);
}

__device__ __forceinline__ u32 pack2(float a, float b){
  return (u32)f2bf(a) | ((u32)f2bf(b) << 16);
}

__device__ __forceinline__ void gload_lds16(const void* g, void* l){
  __builtin_amdgcn_global_load_lds(
      (const __attribute__((address_space(1))) u32*)g,
      (__attribute__((address_space(3))) u32*)l, 16, 0, 0);
}

// ---------------- xPos tables: packed (c,s) float2, [pos][hi=128] ----------
__global__ void k_tables(float2* __restrict__ tq2, float2* __restrict__ tk2){
  int idx = blockIdx.x * 256 + threadIdx.x;     // 2048*128 = 262144
  int n = idx >> 7, hi = idx & 127;
  float fn = (float)n, fi = (float)hi;
  float invf = exp2f(-(fi * (1.0f/128.0f)) * 13.2877124f);   // 10000^(-hi/128)
  float ang = fn * invf;
  float s = sinf(ang), c = cosf(ang);
  float sv = (2.0f * fi + 102.4f) * (1.0f / 358.4f);
  float sc = exp2f((fn * (1.0f/512.0f)) * log2f(sv));
  float2 q; q.x = c * sc;  q.y = s * sc;
  tq2[idx] = q;
  float inv = 1.0f / sc;
  float2 k; k.x = c * inv; k.y = s * inv;
  tk2[idx] = k;
}

// -------- W -> bf16 chunk-planar pre-swizzled image Wt2[kc][col768][p][8] ----
__global__ void k_wt(const float* __restrict__ wq, const float* __restrict__ wk,
                     const float* __restrict__ wv, u16* __restrict__ wt2){
  int idx = blockIdx.x * 256 + threadIdx.x;     // 4*768*8 = 24576 chunks
  int kc = idx / 6144, r = idx % 6144;
  int col = r >> 3, p = r & 7;
  int j = p ^ (col & 7);
  int wsel = col >> 8, c = col & 255;
  const float* src = (wsel == 0) ? wq : ((wsel == 1) ? wk : wv);
  int k0 = kc * 64 + j * 8;
  u32x4 v;
  v.x = pack2(src[(k0+0)*256 + c], src[(k0+1)*256 + c]);
  v.y = pack2(src[(k0+2)*256 + c], src[(k0+3)*256 + c]);
  v.z = pack2(src[(k0+4)*256 + c], src[(k0+5)*256 + c]);
  v.w = pack2(src[(k0+6)*256 + c], src[(k0+7)*256 + c]);
  *(u32x4*)(wt2 + (size_t)idx * 8) = v;
}

// -------- X -> bf16 chunk-planar pre-swizzled image Xb2[kc][row][p][8] ------
__global__ void k_xbf(const float* __restrict__ X, u16* __restrict__ Xb2){
  int idx = blockIdx.x * 256 + threadIdx.x;     // 65536*32 chunk ids
  int row = idx >> 5, g = idx & 31;
  int kc = g >> 3, j = g & 7;
  int p = j ^ (row & 7);
  const float4* src = (const float4*)(X + (size_t)row * 256 + g * 8);
  float4 a = src[0], b = src[1];
  u32x4 v;
  v.x = pack2(a.x, a.y); v.y = pack2(a.z, a.w);
  v.z = pack2(b.x, b.y); v.w = pack2(b.z, b.w);
  *(u32x4*)(Xb2 + (((size_t)kc * 65536 + row) * 8 + p) * 8) = v;
}

// ---------------- fused QKV projection + xPos (+ V transpose) -------------
// One GEMM: A = X (65536x256), B = [WQ|WK|WV] (256x768). 1D grid 3072,
// XCD-chunked swizzle, logical id l -> (ct = l%6 fastest, rt = l/6) so the
// 6 coltile-blocks sharing an X rowtile run adjacently on one XCD.
// Block 256 (4 waves, 2x2), tile 128x128, wave 64x64 (64 AGPR acc).
// K staged in 4 chunks of 64, DOUBLE-BUFFERED (stage kc+1 before compute kc).
__global__ __launch_bounds__(256, 2) void k_proj(
    const u16* __restrict__ Xb2, const u16* __restrict__ Wt2,
    const float2* __restrict__ tq2, const float2* __restrict__ tk2,
    u16* __restrict__ Qx, u16* __restrict__ Kx, u16* __restrict__ VT)
{
  __shared__ u16 ldsX[2][8192];                 // 2 x 16 KiB
  __shared__ u16 ldsW[2][8192];                 // 2 x 16 KiB
  const int p0 = blockIdx.x;                    // 0..3071
  const int l = (p0 & 7) * 384 + (p0 >> 3);     // bijective XCD chunking
  const int ct = l % 6;                         // 0..5 (fastest)
  const int rt = l / 6;                         // 0..511
  const int wsel = ct >> 1;
  const int mcol0 = (ct & 1) * 128;
  const int row0 = rt * 128;
  const int bh = rt >> 4;
  const int tid = threadIdx.x;
  const int lane = tid & 63, wid = tid >> 6;
  const int h = lane >> 4, l15 = lane & 15;
  const int wrg = wid >> 1, wcg = wid & 1;

  f32x4 acc[4][4] = {};                         // 64 AGPR

  auto stage = [&](int kc, int buf){
    const u16* xsrc = Xb2 + ((size_t)kc * 65536 + row0) * 64;
    const u16* wsrc = Wt2 + ((size_t)kc * 768 + ct * 128) * 64;
#pragma unroll
    for (int t = 0; t < 4; ++t){
      int ci = t * 256 + tid;
      gload_lds16(xsrc + ci * 8, (char*)ldsX[buf] + (t * 256 + wid * 64) * 16);
      gload_lds16(wsrc + ci * 8, (char*)ldsW[buf] + (t * 256 + wid * 64) * 16);
    }
  };

  stage(0, 0);
  __syncthreads();                              // drains vmcnt(0)

  for (int kc = 0; kc < 4; ++kc){
    const int cur = kc & 1;
    if (kc < 3) stage(kc + 1, cur ^ 1);         // async, hides under MFMA

#pragma unroll
    for (int kb = 0; kb < 2; ++kb){
      bf16x8 xf[4], wf[4];
#pragma unroll
      for (int b = 0; b < 4; ++b){
        int r = wrg * 64 + b * 16 + l15;
        int p = (kb * 4 + h) ^ (r & 7);
        xf[b] = *(const bf16x8*)((const char*)ldsX[cur] + r * 128 + p * 16);
      }
#pragma unroll
      for (int a = 0; a < 4; ++a){
        int c = wcg * 64 + a * 16 + l15;
        int p = (kb * 4 + h) ^ (c & 7);
        wf[a] = *(const bf16x8*)((const char*)ldsW[cur] + c * 128 + p * 16);
      }
      if (wsel < 2){
#pragma unroll
        for (int a = 0; a < 4; ++a)
#pragma unroll
          for (int b = 0; b < 4; ++b)
            acc[a][b] = __builtin_amdgcn_mfma_f32_16x16x32_bf16(
                wf[a], xf[b], acc[a][b], 0, 0, 0);
      } else {
#pragma unroll
        for (int b = 0; b < 4; ++b)
#pragma unroll
          for (int a = 0; a < 4; ++a)
            acc[b][a] = __builtin_amdgcn_mfma_f32_16x16x32_bf16(
                xf[b], wf[a], acc[b][a], 0, 0, 0);
      }
    }
    __syncthreads();                            // waits next-stage + readers
  }

  if (wsel == 2){
    // V: acc[b=posfrag][a=dfrag]; lane holds 4 consecutive pos at fixed d
#pragma unroll
    for (int b = 0; b < 4; ++b){
      int pos0 = (row0 + wrg * 64 + b * 16 + h * 4) & 2047;
#pragma unroll
      for (int a = 0; a < 4; ++a){
        int d = mcol0 + wcg * 64 + a * 16 + l15;
        f32x4 v = acc[b][a];
        u32x2 p2; p2.x = pack2(v.x, v.y); p2.y = pack2(v.z, v.w);
        *(u32x2*)(VT + ((size_t)bh * DMODEL + d) * 2048 + pos0) = p2;
      }
    }
  } else {
    // Q/K: acc[a=dfrag][b=posfrag]; lane holds 4 consecutive d at fixed pos
    const float2* tt = (wsel == 0) ? tq2 : tk2;
    u16* Od = (wsel == 0) ? Qx : Kx;
#pragma unroll
    for (int a = 0; a < 4; ++a){
      int d0 = mcol0 + wcg * 64 + a * 16 + h * 4;
#pragma unroll
      for (int b = 0; b < 4; ++b){
        int n = row0 + wrg * 64 + b * 16 + l15;
        int pos = n & 2047;
        f32x4 v = acc[a][b];
        float4 t = *(const float4*)(tt + pos * 128 + (d0 >> 1));
        float y0 = v.x * t.x - v.y * t.y;
        float y1 = v.y * t.x + v.x * t.y;
        float y2 = v.z * t.z - v.w * t.w;
        float y3 = v.w * t.z + v.z * t.w;
        u32x2 p2; p2.x = pack2(y0, y1); p2.y = pack2(y2, y3);
        *(u32x2*)(Od + (size_t)n * 256 + d0) = p2;
      }
    }
  }
}

// ---------------- banded decayed attention ----------------
// grid 512 = 32 bh * 16 n-chunks(128), XCD-chunked swizzle (adjacent i on
// one XCD -> K/V tile L2 reuse). block 512 (8 waves x 16 rows).
// K/V LDS DOUBLE-BUFFERED (128 KiB, free: regs already cap at 1 block/CU):
// stage j+1 issued before compute of j, one barrier per tile.
__global__ __launch_bounds__(512) void k_attn(
    const u16* __restrict__ Qx, const u16* __restrict__ Kx,
    const u16* __restrict__ VT, float* __restrict__ out)
{
  __shared__ char smem[131072];     // K0,K1 @0/32K; V0,V1 @64K/96K

  const int pbid = blockIdx.x;
  const int bid = ((pbid & 7) << 6) | (pbid >> 3);   // bijective, 512=8*64
  const int bh = bid >> 4, i = bid & 15;
  const int tid = threadIdx.x;
  const int lane = tid & 63, w = tid >> 6;
  const int h = lane >> 4, l15 = lane & 15;
  const int n_g = i * 128 + w * 16 + l15;

  // Q B-fragments (k-contiguous from row n_g)
  bf16x8 q[8];
  const u16* qbase = Qx + ((size_t)bh * 2048 + n_g) * 256;
#pragma unroll
  for (int kb = 0; kb < 8; ++kb)
    q[kb] = *(const bf16x8*)(qbase + kb * 32 + h * 8);

  f32x4 ot[16] = {};   // O^T: 16 d-tiles x (16d x 16n)

  int j_lo = 2 * i - 4; if (j_lo < 0) j_lo = 0;
  const int j_hi = 2 * i + 1;
  const float L2G = -0.04580369f;          // log2(0.96875)
  const float GI1 = 1.03225806f;           // gamma^-1
  const float GI2 = 1.06555671f;           // gamma^-2
  const float GI3 = 1.09993040f;           // gamma^-3

  auto stage = [&](int j, int buf){
    const u16* kbase = Kx + ((size_t)bh * 2048 + j * 64) * 256;
    char* kdst = smem + buf * 32768;
#pragma unroll
    for (int t = 0; t < 4; ++t){
      int s = (w * 4 + t) * 64 + lane;
      int m = s >> 5, c = s & 31;
      gload_lds16(kbase + m * 256 + ((c ^ (m & 7)) * 8),
                  kdst + (w * 4 + t) * 1024);
    }
    const u16* vbase = VT + (size_t)bh * (DMODEL * 2048) + j * 64;
    char* vdst = smem + 65536 + buf * 32768;
#pragma unroll
    for (int t = 0; t < 4; ++t){
      int s = (w * 4 + t) * 64 + lane;
      int d = s >> 3, c = s & 7;
      gload_lds16(vbase + (size_t)d * 2048 + ((c ^ (d & 7)) * 8),
                  vdst + (w * 4 + t) * 1024);
    }
  };

  stage(j_lo, 0);
  __syncthreads();                         // drains vmcnt(0)

  for (int j = j_lo; j <= j_hi; ++j){
    const int cur = (j - j_lo) & 1;
    if (j < j_hi) stage(j + 1, cur ^ 1);   // async prefetch next tile

    if (i * 128 + w * 16 + 15 >= j * 64){  // wave has any unmasked pairs
      const char* ldsK = smem + cur * 32768;
      const char* ldsV = smem + 65536 + cur * 32768;
      // ---- S^T = K · Q^T  (4 m-tiles x K=256)
      f32x4 sacc[4] = {};
#pragma unroll
      for (int kb = 0; kb < 8; ++kb){
#pragma unroll
        for (int mt = 0; mt < 4; ++mt){
          int m = mt * 16 + l15;
          int chunk = kb * 4 + h;
          bf16x8 a = *(const bf16x8*)(ldsK + m * 512 +
                                      ((chunk ^ (m & 7)) * 16));
          sacc[mt] = __builtin_amdgcn_mfma_f32_16x16x32_bf16(
              a, q[kb], sacc[mt], 0, 0, 0);
        }
      }
      // ---- decay weight + pack to bf16 pairs (per group of 4 m)
      u32 dA[4], dB[4];
#pragma unroll
      for (int mt = 0; mt < 4; ++mt){
        int m0 = j * 64 + mt * 16 + h * 4;
        int dl = n_g - m0;
        float base = exp2f((float)dl * L2G);       // gamma^dl
        float v0 = (dl     >= 0) ? sacc[mt].x * base       : 0.0f;
        float v1 = (dl - 1 >= 0) ? sacc[mt].y * base * GI1 : 0.0f;
        float v2 = (dl - 2 >= 0) ? sacc[mt].z * base * GI2 : 0.0f;
        float v3 = (dl - 3 >= 0) ? sacc[mt].w * base * GI3 : 0.0f;
        dA[mt] = pack2(v0, v1);
        dB[mt] = pack2(v2, v3);
      }
      // ---- build PV B-frags in-register (shuffle S^T C-layout -> B-layout)
      int s0 = l15 + 32 * (h & 1);
      int s1 = s0 + 16;
      bool lo = (h < 2);
#pragma unroll
      for (int kt = 0; kt < 2; ++kt){
        u32 a0 = (u32)__shfl((int)dA[2 * kt],     s0, 64);
        u32 a1 = (u32)__shfl((int)dA[2 * kt + 1], s0, 64);
        u32 b0 = (u32)__shfl((int)dB[2 * kt],     s0, 64);
        u32 b1 = (u32)__shfl((int)dB[2 * kt + 1], s0, 64);
        u32 a2 = (u32)__shfl((int)dA[2 * kt],     s1, 64);
        u32 a3 = (u32)__shfl((int)dA[2 * kt + 1], s1, 64);
        u32 b2 = (u32)__shfl((int)dB[2 * kt],     s1, 64);
        u32 b3 = (u32)__shfl((int)dB[2 * kt + 1], s1, 64);
        union { u32 u[4]; bf16x8 v; } uu;
        uu.u[0] = lo ? a0 : a1;
        uu.u[1] = lo ? b0 : b1;
        uu.u[2] = lo ? a2 : a3;
        uu.u[3] = lo ? b2 : b3;
        bf16x8 bfrag = uu.v;
        // ---- O^T += V^T · P^T
#pragma unroll
        for (int dt = 0; dt < 16; ++dt){
          int d = dt * 16 + l15;
          int chunk = kt * 4 + h;
          bf16x8 a = *(const bf16x8*)(ldsV + d * 128 +
                                      ((chunk ^ (d & 7)) * 16));
          ot[dt] = __builtin_amdgcn_mfma_f32_16x16x32_bf16(
              a, bfrag, ot[dt], 0, 0, 0);
        }
      }
    }
    __syncthreads();                       // drains prefetch + readers done
  }

  // ---- write O (f32): lane holds 4 consecutive d at fixed n -> float4
  float* obase = out + ((size_t)bh * 2048 + n_g) * 256;
#pragma unroll
  for (int dt = 0; dt < 16; ++dt)
    *(f32x4*)(obase + dt * 16 + h * 4) = ot[dt];
}

// ---------------- launch ----------------
extern "C" void kernel_launch(void* const* d_in, const int* in_sizes, int n_in,
                              void* d_out, int out_size, void* d_ws, size_t ws_size,
                              hipStream_t stream)
{
  (void)in_sizes; (void)n_in; (void)out_size; (void)ws_size;
  const float* X  = (const float*)d_in[0];
  const float* WQ = (const float*)d_in[1];
  const float* WK = (const float*)d_in[2];
  const float* WV = (const float*)d_in[3];
  float* out = (float*)d_out;

  char* ws = (char*)d_ws;
  float2* tq2 = (float2*)ws;                     // 2 MiB  [2048][128] (c,s)
  float2* tk2 = (float2*)(ws + (2u << 20));      // 2 MiB
  u16* wt2 = (u16*)(ws + (4u << 20));            // 384 KiB chunk-planar
  u16* qx = (u16*)(ws + 4718592);                // 32 MiB
  u16* kx = (u16*)(ws + 38273024);               // 32 MiB
  u16* vt = (u16*)(ws + 71827456);               // 32 MiB  (end ~100.5 MiB)

  // Xb2 (32 MiB) lives in d_out (64 MiB): written by k_xbf, consumed by
  // k_proj, then fully overwritten by k_attn's output. Deterministic.
  u16* xb2 = (u16*)d_out;

  k_tables<<<dim3(1024), dim3(256), 0, stream>>>(tq2, tk2);
  k_wt<<<dim3(96), dim3(256), 0, stream>>>(WQ, WK, WV, wt2);
  k_xbf<<<dim3(8192), dim3(256), 0, stream>>>(X, xb2);
  k_proj<<<dim3(3072), dim3(256), 0, stream>>>(xb2, wt2, tq2, tk2, qx, kx, vt);
  k_attn<<<dim3(512), dim3(512), 0, stream>>>(qx, kx, vt, out);
}